// Round 3
// baseline (210.670 us; speedup 1.0000x reference)
//
#include <hip/hip_runtime.h>
#include <stdint.h>

typedef unsigned int  uint32;
typedef unsigned short u16;
typedef __attribute__((ext_vector_type(8))) short short8;
typedef __attribute__((ext_vector_type(4))) float f32x4;
typedef __attribute__((ext_vector_type(4))) _Float16 half4;

// ---------- helpers ----------
__device__ __forceinline__ float bits2f(uint32 u){ union{uint32 u; float f;} c; c.u=u; return c.f; }
__device__ __forceinline__ uint32 f2bits(float f){ union{uint32 u; float f;} c; c.f=f; return c.u; }
__device__ __forceinline__ u16 f2b(float f){ uint32 u=f2bits(f); return (u16)((u + 0x7FFFu + ((u>>16)&1u))>>16); }
__device__ __forceinline__ float b2f(u16 h){ return bits2f(((uint32)h)<<16); }
__device__ __forceinline__ u16 f2h(float f){ _Float16 h=(_Float16)f; union{u16 u; _Float16 h;} c; c.h=h; return c.u; }
__device__ __forceinline__ float4 ld4f(const float* p){ return *(const float4*)p; }
#define BLO(u) bits2f((u)<<16)
#define BHI(u) bits2f((u)&0xFFFF0000u)

#define QKS 24

// ---------- fold raw BN sums into per-channel affine in LDS ----------
__device__ __forceinline__ void load_ab(const float* __restrict__ gacc,
                                        const float* __restrict__ gam,
                                        const float* __restrict__ bet,
                                        float* sA, float* sB, int t)
{
  if (t < 128) {
    const float mean = gacc[t] * (1.f/32768.f);
    const float var  = gacc[128 + t] * (1.f/32768.f) - mean * mean;
    const float rstd = rsqrtf(var + 1e-5f);
    const float Ac = gam[t] * rstd;
    sA[t] = Ac;
    sB[t] = bet[t] - mean * Ac;
  }
  __syncthreads();
}

// ---------- GEMM tile: 128 x (JT*32), BK=64, 4 waves, 16x16x32 bf16 MFMA ----------
// OMODE: 0 bf16 row-major | 2 f16 [T][M][N][D] (*oscale) | 3 f16 [T][M][D][N]
// RES: 0 none | 1 f32 stride128 | 3 bf16 stride128 * BN affine (sA/sB)
// AF32: A fp32 convert in staging. WF32: W fp32 convert in staging.
// BNA: BN affine on A channels (K==128, sA/sB). STATS: channel sums -> gacc atomics.
template<int OMODE, int RES, bool RELU, bool AF32, bool WF32, bool BNA, bool STATS, int JT>
__device__ __forceinline__ void gemm_tile(
    u16* As, u16* Ws, const float* sA, const float* sB, float* pS, float* pQ,
    const void* Ain, const void* W, const float* bias, const void* res,
    float* gacc_out, void* out, int row0, int col0, int K, int Nout,
    float oscale, int t)
{
  constexpr int WROWS = JT * 32;
  const int L = t & 63, w = t >> 6;
  const int wrow = (w >> 1) * 64, wcol = (w & 1) * (JT * 16);
  const int lm = L & 15, lg = L >> 4;

  f32x4 acc[4][JT];
#pragma unroll
  for (int i = 0; i < 4; ++i)
#pragma unroll
    for (int j = 0; j < JT; ++j) acc[i][j] = (f32x4){0.f,0.f,0.f,0.f};

  const int srow = t >> 1, skc = (t & 1) * 32;
  const u16*   Ab = (const u16*)Ain + (size_t)(row0 + srow) * K + skc;
  const float* Af = (const float*)Ain + (size_t)(row0 + srow) * K + skc;
  u16* Asp = As + srow * 72 + skc;
  constexpr int TPR = 256 / WROWS;
  const int wsrow = t / TPR, wskc = (t % TPR) * (64 / TPR);
  const u16*   Wp  = (const u16*)W + (size_t)(col0 + wsrow) * K + wskc;
  const float* Wpf = (const float*)W + (size_t)(col0 + wsrow) * K + wskc;
  u16* Wsp = Ws + wsrow * 72 + wskc;
  constexpr int NW = (64 / TPR) / 8;

  // one K-chunk of raw staging data held in registers (in-flight chunk)
  short8 ga[4]; short8 gw[NW];
  float4 fa[4][2]; float4 fw[NW][2];

  auto load_chunk = [&](int k0) {
    if constexpr (AF32) {
#pragma unroll
      for (int i = 0; i < 4; ++i) {
        fa[i][0] = ld4f(Af + k0 + i*8);
        fa[i][1] = ld4f(Af + k0 + i*8 + 4);
      }
    } else {
#pragma unroll
      for (int i = 0; i < 4; ++i) ga[i] = *(const short8*)(Ab + k0 + i*8);
    }
    if constexpr (WF32) {
#pragma unroll
      for (int i = 0; i < NW; ++i) {
        fw[i][0] = ld4f(Wpf + k0 + i*8);
        fw[i][1] = ld4f(Wpf + k0 + i*8 + 4);
      }
    } else {
#pragma unroll
      for (int i = 0; i < NW; ++i) gw[i] = *(const short8*)(Wp + k0 + i*8);
    }
  };

  auto write_chunk = [&](int k0) {
    if constexpr (AF32) {
#pragma unroll
      for (int i = 0; i < 4; ++i) {
        short8 s;
        s[0]=(short)f2b(fa[i][0].x); s[1]=(short)f2b(fa[i][0].y);
        s[2]=(short)f2b(fa[i][0].z); s[3]=(short)f2b(fa[i][0].w);
        s[4]=(short)f2b(fa[i][1].x); s[5]=(short)f2b(fa[i][1].y);
        s[6]=(short)f2b(fa[i][1].z); s[7]=(short)f2b(fa[i][1].w);
        *(short8*)(Asp + i*8) = s;
      }
    } else if constexpr (BNA) {
#pragma unroll
      for (int i = 0; i < 4; ++i) {
        const int c = skc + k0 + i*8;   // channel (K == 128)
        const short8 x8 = ga[i];
        const float4 A0 = *(const float4*)&sA[c], A1 = *(const float4*)&sA[c+4];
        const float4 B0 = *(const float4*)&sB[c], B1 = *(const float4*)&sB[c+4];
        short8 s;
        s[0]=(short)f2b(b2f((u16)x8[0])*A0.x+B0.x); s[1]=(short)f2b(b2f((u16)x8[1])*A0.y+B0.y);
        s[2]=(short)f2b(b2f((u16)x8[2])*A0.z+B0.z); s[3]=(short)f2b(b2f((u16)x8[3])*A0.w+B0.w);
        s[4]=(short)f2b(b2f((u16)x8[4])*A1.x+B1.x); s[5]=(short)f2b(b2f((u16)x8[5])*A1.y+B1.y);
        s[6]=(short)f2b(b2f((u16)x8[6])*A1.z+B1.z); s[7]=(short)f2b(b2f((u16)x8[7])*A1.w+B1.w);
        *(short8*)(Asp + i*8) = s;
      }
    } else {
#pragma unroll
      for (int i = 0; i < 4; ++i) *(short8*)(Asp + i*8) = ga[i];
    }
    if constexpr (WF32) {
#pragma unroll
      for (int i = 0; i < NW; ++i) {
        short8 s;
        s[0]=(short)f2b(fw[i][0].x); s[1]=(short)f2b(fw[i][0].y);
        s[2]=(short)f2b(fw[i][0].z); s[3]=(short)f2b(fw[i][0].w);
        s[4]=(short)f2b(fw[i][1].x); s[5]=(short)f2b(fw[i][1].y);
        s[6]=(short)f2b(fw[i][1].z); s[7]=(short)f2b(fw[i][1].w);
        *(short8*)(Wsp + i*8) = s;
      }
    } else {
#pragma unroll
      for (int i = 0; i < NW; ++i) *(short8*)(Wsp + i*8) = gw[i];
    }
  };

  load_chunk(0);
  for (int k0 = 0; k0 < K; k0 += 64) {
    __syncthreads();   // previous chunk fully consumed
    write_chunk(k0);
    __syncthreads();
    if (k0 + 64 < K) load_chunk(k0 + 64);   // prefetch: hides under MFMA below
#pragma unroll
    for (int ks = 0; ks < 64; ks += 32) {
      short8 af[4], wf[JT];
#pragma unroll
      for (int i = 0; i < 4; ++i)
        af[i] = *(const short8*)(As + (wrow + i*16 + lm) * 72 + ks + lg*8);
#pragma unroll
      for (int j = 0; j < JT; ++j)
        wf[j] = *(const short8*)(Ws + (wcol + j*16 + lm) * 72 + ks + lg*8);
#pragma unroll
      for (int i = 0; i < 4; ++i)
#pragma unroll
        for (int j = 0; j < JT; ++j)
          acc[i][j] = __builtin_amdgcn_mfma_f32_16x16x32_bf16(af[i], wf[j], acc[i][j], 0, 0, 0);
    }
  }

  float bj[JT];
#pragma unroll
  for (int j = 0; j < JT; ++j) bj[j] = bias[col0 + wcol + j*16 + lm];

  float stS[JT], stQ[JT];
#pragma unroll
  for (int j = 0; j < JT; ++j) { stS[j] = 0.f; stQ[j] = 0.f; }

#pragma unroll
  for (int i = 0; i < 4; ++i) {
    const int rowb = row0 + wrow + i*16 + lg*4;
#pragma unroll
    for (int j = 0; j < JT; ++j) {
      const int col = col0 + wcol + j*16 + lm;
      float ra = 0.f, rb = 0.f;
      if constexpr (RES == 3) { ra = sA[col & 127]; rb = sB[col & 127]; }
      if constexpr (OMODE == 3) {   // f16 [T][M][D][N]
        const int tt = rowb >> 8, n0 = rowb & 255;
        const int mh = col >> 4, d = col & 15;
        uint2 o;
        o.x = (uint32)f2h(acc[i][j][0] + bj[j]) | ((uint32)f2h(acc[i][j][1] + bj[j]) << 16);
        o.y = (uint32)f2h(acc[i][j][2] + bj[j]) | ((uint32)f2h(acc[i][j][3] + bj[j]) << 16);
        *(uint2*)((u16*)out + (((size_t)tt*8 + mh)*16 + d)*256 + n0) = o;
      } else {
#pragma unroll
        for (int r = 0; r < 4; ++r) {
          const int row = rowb + r;
          float v = acc[i][j][r] + bj[j];
          if constexpr (RES == 1) v += ((const float*)res)[(size_t)row*128 + col];
          if constexpr (RES == 3) v += b2f(((const u16*)res)[(size_t)row*128 + col]) * ra + rb;
          if constexpr (RELU) v = fmaxf(v, 0.f);
          if constexpr (STATS) { stS[j] += v; stQ[j] += v*v; }
          if constexpr (OMODE == 2) {
            const int tt = row >> 8, n = row & 255, mh = col >> 4, d = col & 15;
            ((u16*)out)[(((size_t)tt*8 + mh)*256 + n)*16 + d] = f2h(v * oscale);
          } else {
            ((u16*)out)[(size_t)row * Nout + col] = f2b(v);
          }
        }
      }
    }
  }

  if constexpr (STATS) {   // Nout == 128
    __syncthreads();
    if (t < 128) { pS[t] = 0.f; pQ[t] = 0.f; }
    __syncthreads();
#pragma unroll
    for (int j = 0; j < JT; ++j) {
      const int col = col0 + wcol + j*16 + lm;
      atomicAdd(&pS[col], stS[j]);
      atomicAdd(&pQ[col], stQ[j]);
    }
    __syncthreads();
    if (t < 128) {
      atomicAdd(&gacc_out[t],       pS[t]);
      atomicAdd(&gacc_out[128 + t], pQ[t]);
    }
  }
}

// ---------- node 1: QKV projections (W fp32 in staging) + cvt(Ww,Wf1,Wf2) + zero accbuf ----------
__global__ __launch_bounds__(256)
void qkv_k(const float* __restrict__ node,
           const float* __restrict__ Wq, const float* __restrict__ bq,
           const float* __restrict__ Wk, const float* __restrict__ bk,
           const float* __restrict__ Wv, const float* __restrict__ bv,
           const float* __restrict__ Ww, const float* __restrict__ Wf1,
           const float* __restrict__ Wf2,
           u16* __restrict__ qb, u16* __restrict__ kb, u16* __restrict__ vb,
           u16* __restrict__ wb, float* __restrict__ accbuf)
{
  const int bid = blockIdx.x, t = threadIdx.x;
  if (bid < 768) {
    __shared__ u16 As[128*72];
    __shared__ u16 Ws[128*72];
    __shared__ __align__(16) float sA[128], sB[128];
    __shared__ float pS[128], pQ[128];
    const int x = bid & 255, y = bid >> 8;
    const float QSCALE = 0.36067376022224085f;  // 0.25 * log2(e)
    if (y == 0)
      gemm_tile<2,0,false,true,true,false,false,4>(As,Ws,sA,sB,pS,pQ, node, Wq, bq,
          nullptr, nullptr, qb, x*128, 0, 128, 128, QSCALE, t);
    else if (y == 1)
      gemm_tile<2,0,false,true,true,false,false,4>(As,Ws,sA,sB,pS,pQ, node, Wk, bk,
          nullptr, nullptr, kb, x*128, 0, 128, 128, 1.f, t);
    else
      gemm_tile<3,0,false,true,true,false,false,4>(As,Ws,sA,sB,pS,pQ, node, Wv, bv,
          nullptr, nullptr, vb, x*128, 0, 128, 128, 1.f, t);
  } else if (bid < 912) {
    // convert Ww/Wf1/Wf2 fp32 -> bf16 into wb (layout: Ww@49152, Wf1@65536, Wf2@131072 u16)
    const int i = (bid - 768) * 256 + t;   // 0..36863 float4
    const float4* src; u16* dst;
    if      (i <  4096) { src = (const float4*)Ww  + i;         dst = wb +  49152 + (size_t)i*4; }
    else if (i < 20480) { src = (const float4*)Wf1 + (i-4096);  dst = wb +  65536 + (size_t)(i-4096)*4; }
    else                { src = (const float4*)Wf2 + (i-20480); dst = wb + 131072 + (size_t)(i-20480)*4; }
    float4 v = *src;
    uint2 o;
    o.x = (uint32)f2b(v.x) | ((uint32)f2b(v.y) << 16);
    o.y = (uint32)f2b(v.z) | ((uint32)f2b(v.w) << 16);
    *(uint2*)dst = o;
  } else {
    accbuf[t] = 0.f;
    accbuf[256 + t] = 0.f;
  }
}

// ---------- out-proj: + node residual, BN1 stats.  128x64 tiles -> 512 blocks ----------
__global__ __launch_bounds__(256)
void oproj_k(const u16* __restrict__ ab, const u16* __restrict__ wwb,
             const float* __restrict__ bw, const float* __restrict__ node,
             float* __restrict__ accbuf, u16* __restrict__ xb)
{
  __shared__ u16 As[128*72];
  __shared__ u16 Ws[64*72];
  __shared__ __align__(16) float sA[128], sB[128];
  __shared__ float pS[128], pQ[128];
  gemm_tile<0,1,false,false,false,false,true,2>(As,Ws,sA,sB,pS,pQ, ab, wwb, bw,
      node, accbuf, xb, blockIdx.x*128, blockIdx.y*64, 128, 128, 1.f, threadIdx.x);
}

// ---------- fused FFN: per 64-row slice, hidden kept in LDS ----------
// Phase 1: h = relu(BN1(xb) @ Wf1^T + bf1)  -> Hs (LDS, bf16)
// Phase 2: x2 = h @ Wf2^T + bf2 + BN1(xb)   -> x2b, BN2 stats -> acc2
// 512 threads (8 waves), grid 512 (64 rows each). LDS ~102 KB -> 1 block/CU.
#define HS_LD 520   // 64 x 520 u16 : bank-stride 4 on row reads (2-way, free)
#define AS_LD 136   // 64 x 136 u16
#define WS_LD 72    // 128 x 72 u16

__global__ __launch_bounds__(512)
void ffn_k(const u16* __restrict__ xb, const u16* __restrict__ wf1b,
           const float* __restrict__ bf1, const u16* __restrict__ wf2b,
           const float* __restrict__ bf2, const float* __restrict__ accbuf,
           const float* __restrict__ g1, const float* __restrict__ be1,
           float* __restrict__ acc2, u16* __restrict__ x2b)
{
  __shared__ u16 Hs[64*HS_LD];
  __shared__ u16 As[64*AS_LD];
  __shared__ u16 Ws[128*WS_LD];
  __shared__ __align__(16) float sA[128], sB[128];
  __shared__ float pS[128], pQ[128];

  const int t = threadIdx.x;
  const int row0 = blockIdx.x * 64;
  load_ab(accbuf, g1, be1, sA, sB, t);   // BN1 affine (includes __syncthreads)

  // ---- stage A = BN1(xb[row0 .. row0+64][0:128]) into As, once ----
  {
    const int r = t >> 3, seg = (t & 7) * 16;   // 16 values / thread
    const u16* src = xb + (size_t)(row0 + r) * 128 + seg;
    u16* dst = As + r * AS_LD + seg;
#pragma unroll
    for (int h = 0; h < 2; ++h) {
      const short8 x8 = *(const short8*)(src + h*8);
      const int c = seg + h*8;
      const float4 A0 = *(const float4*)&sA[c], A1 = *(const float4*)&sA[c+4];
      const float4 B0 = *(const float4*)&sB[c], B1 = *(const float4*)&sB[c+4];
      short8 s;
      s[0]=(short)f2b(b2f((u16)x8[0])*A0.x+B0.x); s[1]=(short)f2b(b2f((u16)x8[1])*A0.y+B0.y);
      s[2]=(short)f2b(b2f((u16)x8[2])*A0.z+B0.z); s[3]=(short)f2b(b2f((u16)x8[3])*A0.w+B0.w);
      s[4]=(short)f2b(b2f((u16)x8[4])*A1.x+B1.x); s[5]=(short)f2b(b2f((u16)x8[5])*A1.y+B1.y);
      s[6]=(short)f2b(b2f((u16)x8[6])*A1.z+B1.z); s[7]=(short)f2b(b2f((u16)x8[7])*A1.w+B1.w);
      *(short8*)(dst + h*8) = s;
    }
  }

  const int w = t >> 6, L = t & 63, lm = L & 15, lg = L >> 4;
  const int wcol = w * 16;            // 8 waves x 16 cols = 128 output cols
  const int wr = t >> 2, kc = (t & 3) * 16;   // W staging: 128 rows x 64 k / 512 thr

  // W chunk source: cc in [0,16): cc<8 -> Wf1 (ct=cc>>1, k0=(cc&1)*64); else Wf2
  auto wsrc = [&](int cc) -> const u16* {
    if (cc < 8) return wf1b + (size_t)((cc>>1)*128 + wr)*128 + (cc&1)*64 + kc;
    return wf2b + (size_t)wr*512 + (cc-8)*64 + kc;
  };

  f32x4 accF[4];
#pragma unroll
  for (int i = 0; i < 4; ++i) accF[i] = (f32x4){0.f,0.f,0.f,0.f};

  short8 gw0 = *(const short8*)(wsrc(0));
  short8 gw1 = *(const short8*)(wsrc(0) + 8);

  for (int cc = 0; cc < 16; ++cc) {
    __syncthreads();                       // Ws (and As/Hs writes) consumed/visible
    *(short8*)(Ws + wr*WS_LD + kc)     = gw0;
    *(short8*)(Ws + wr*WS_LD + kc + 8) = gw1;
    __syncthreads();
    if (cc < 15) {                         // prefetch next W chunk
      gw0 = *(const short8*)(wsrc(cc+1));
      gw1 = *(const short8*)(wsrc(cc+1) + 8);
    }
    const u16* Abase = (cc < 8) ? (As + ((size_t)(cc & 1) * 64))
                                : (Hs + ((size_t)(cc - 8) * 64));
    const int ald = (cc < 8) ? AS_LD : HS_LD;
#pragma unroll
    for (int ks = 0; ks < 64; ks += 32) {
      short8 af[4], wf;
#pragma unroll
      for (int i = 0; i < 4; ++i)
        af[i] = *(const short8*)(Abase + (i*16 + lm) * ald + ks + lg*8);
      wf = *(const short8*)(Ws + (wcol + lm) * WS_LD + ks + lg*8);
#pragma unroll
      for (int i = 0; i < 4; ++i)
        accF[i] = __builtin_amdgcn_mfma_f32_16x16x32_bf16(af[i], wf, accF[i], 0, 0, 0);
    }
    if (cc < 8 && (cc & 1)) {              // ffn1 col-tile done -> relu+bias -> Hs
      const int ct = cc >> 1;
      const float b1 = bf1[ct*128 + wcol + lm];
#pragma unroll
      for (int i = 0; i < 4; ++i) {
#pragma unroll
        for (int r = 0; r < 4; ++r) {
          const int row = i*16 + lg*4 + r;
          Hs[row*HS_LD + ct*128 + wcol + lm] = f2b(fmaxf(accF[i][r] + b1, 0.f));
        }
        accF[i] = (f32x4){0.f,0.f,0.f,0.f};
      }
    }
  }

  // ---- ffn2 epilogue: + BN1(xb) residual, BN2 stats, store x2b ----
  const int col = wcol + lm;
  const float b2 = bf2[col];
  const float ra = sA[col], rb = sB[col];
  float stS = 0.f, stQ = 0.f;
#pragma unroll
  for (int i = 0; i < 4; ++i) {
#pragma unroll
    for (int r = 0; r < 4; ++r) {
      const int row = row0 + i*16 + lg*4 + r;
      float v = accF[i][r] + b2 + b2f(xb[(size_t)row*128 + col]) * ra + rb;
      stS += v; stQ += v*v;
      x2b[(size_t)row*128 + col] = f2b(v);
    }
  }
  __syncthreads();
  if (t < 128) { pS[t] = 0.f; pQ[t] = 0.f; }
  __syncthreads();
  atomicAdd(&pS[col], stS);
  atomicAdd(&pQ[col], stQ);
  __syncthreads();
  if (t < 128) {
    atomicAdd(&acc2[t],       pS[t]);
    atomicAdd(&acc2[128 + t], pQ[t]);
  }
}

// ---------- attention: 1 block per (t,m), 4 waves, f16 16x16x16 MFMA ----------
__global__ __launch_bounds__(256)
void attn_k(const u16* __restrict__ q, const u16* __restrict__ k,
            const u16* __restrict__ v, u16* __restrict__ ab)
{
  __shared__ __align__(16) u16 Qs[256*QKS];
  __shared__ __align__(16) u16 Ks[256*QKS];
  __shared__ __align__(16) u16 Vt[16*264];
  const int tm = blockIdx.x, tt = tm >> 3, m = tm & 7;
  const int t = threadIdx.x;

  const uint4* qg = (const uint4*)(q + (size_t)tm*4096);
  const uint4* kg = (const uint4*)(k + (size_t)tm*4096);
  const uint4* vg = (const uint4*)(v + (size_t)tm*4096);
#pragma unroll
  for (int p = t; p < 512; p += 256) {
    const uint4 a = qg[p], b = kg[p], c = vg[p];
    const int row = p >> 1, h = (p & 1) * 8;
    *(uint4*)(Qs + row*QKS + h) = a;
    *(uint4*)(Ks + row*QKS + h) = b;
    *(uint4*)(Vt + (p >> 5)*264 + (p & 31)*8) = c;
  }
  __syncthreads();

  const int w = t >> 6, L = t & 63, lm = L & 15, quad = L >> 4;

  half4 vf[16];
#pragma unroll
  for (int jt = 0; jt < 16; ++jt)
    vf[jt] = *(const half4*)(Vt + lm*264 + jt*16 + quad*4);

  for (int nt = 0; nt < 4; ++nt) {
    const half4 bq = *(const half4*)(Qs + ((w*4 + nt)*16 + lm)*QKS + quad*4);
    f32x4 s[16];
#pragma unroll
    for (int jt = 0; jt < 16; ++jt) {
      const half4 af = *(const half4*)(Ks + (jt*16 + lm)*QKS + quad*4);
      s[jt] = __builtin_amdgcn_mfma_f32_16x16x16f16(af, bq, (f32x4){0.f,0.f,0.f,0.f}, 0, 0, 0);
    }
    float mx = s[0][0];
#pragma unroll
    for (int jt = 0; jt < 16; ++jt)
#pragma unroll
      for (int r = 0; r < 4; ++r) mx = fmaxf(mx, s[jt][r]);
    mx = fmaxf(mx, __shfl_xor(mx, 16));
    mx = fmaxf(mx, __shfl_xor(mx, 32));
    float ls = 0.f;
#pragma unroll
    for (int jt = 0; jt < 16; ++jt)
#pragma unroll
      for (int r = 0; r < 4; ++r) { const float p = exp2f(s[jt][r] - mx); s[jt][r] = p; ls += p; }
    ls += __shfl_xor(ls, 16);
    ls += __shfl_xor(ls, 32);

    f32x4 oacc = {0.f,0.f,0.f,0.f};
#pragma unroll
    for (int jt = 0; jt < 16; ++jt) {
      half4 pf;
      pf[0] = (_Float16)s[jt][0]; pf[1] = (_Float16)s[jt][1];
      pf[2] = (_Float16)s[jt][2]; pf[3] = (_Float16)s[jt][3];
      oacc = __builtin_amdgcn_mfma_f32_16x16x16f16(pf, vf[jt], oacc, 0, 0, 0);
    }
    const int q0 = w*64 + nt*16 + quad*4;
#pragma unroll
    for (int r = 0; r < 4; ++r) {
      const float lr = __shfl(ls, quad*4 + r);
      ab[((size_t)tt*256 + q0 + r)*128 + m*16 + lm] = f2b(oacc[r] / lr);
    }
  }
}

// ---------- final: BN2 affine + apply bf16 -> fp32 out (512 blocks, uint2 loads) ----------
__global__ __launch_bounds__(256)
void bn_final(const uint2* __restrict__ x2, const float* __restrict__ gacc,
              const float* __restrict__ gam, const float* __restrict__ bet,
              float* __restrict__ out)
{
  __shared__ __align__(16) float sA[128], sB[128];
  const int t = threadIdx.x;
  load_ab(gacc, gam, bet, sA, sB, t);
#pragma unroll 2
  for (int kk = 0; kk < 8; ++kk) {
    const size_t idx = (size_t)blockIdx.x * 2048 + kk * 256 + t;
    const uint2 u = x2[idx];
    const int c = (int)((idx & 31) * 4);   // 4 consecutive channels, 16B aligned
    const f32x4 A = *(const f32x4*)&sA[c];
    const f32x4 B = *(const f32x4*)&sB[c];
    f32x4 o;
    o[0] = BLO(u.x)*A[0] + B[0];
    o[1] = BHI(u.x)*A[1] + B[1];
    o[2] = BLO(u.y)*A[2] + B[2];
    o[3] = BHI(u.y)*A[3] + B[3];
    *(f32x4*)(out + idx*4) = o;
  }
}

// ---------- launch: 5 nodes ----------
extern "C" void kernel_launch(void* const* d_in, const int* in_sizes, int n_in,
                              void* d_out, int out_size, void* d_ws, size_t ws_size,
                              hipStream_t stream)
{
  (void)in_sizes; (void)n_in; (void)out_size; (void)ws_size;
  const float* node = (const float*)d_in[0];
  const float* Wq  = (const float*)d_in[1];  const float* bq  = (const float*)d_in[2];
  const float* Wk  = (const float*)d_in[3];  const float* bk  = (const float*)d_in[4];
  const float* Wv  = (const float*)d_in[5];  const float* bv  = (const float*)d_in[6];
  const float* Ww  = (const float*)d_in[7];  const float* bw  = (const float*)d_in[8];
  const float* Wf1 = (const float*)d_in[9];  const float* bf1 = (const float*)d_in[10];
  const float* Wf2 = (const float*)d_in[11]; const float* bf2 = (const float*)d_in[12];
  const float* g1  = (const float*)d_in[13]; const float* be1 = (const float*)d_in[14];
  const float* g2  = (const float*)d_in[15]; const float* be2 = (const float*)d_in[16];
  float* out = (float*)d_out;
  char* ws = (char*)d_ws;

  // workspace (bytes)
  u16* wb  = (u16*)(ws + 0);          // weights bf16 concat (Ww@49152, Wf1@65536, Wf2@131072 u16)
  u16* qb  = (u16*)(ws + 524288);     // q f16 [T][M][N][D] (pre-scaled)
  u16* kb  = (u16*)(ws + 8912896);    // k f16 [T][M][N][D]
  u16* vb  = (u16*)(ws + 17301504);   // v f16 [T][M][D][N]
  u16* ab  = (u16*)(ws + 25690112);   // attn out bf16 [T][N][E]
  u16* xb  = (u16*)(ws + 34078720);   // x (pre-BN1) bf16
  u16* x2b = (u16*)(ws + 42467328);   // x2 (pre-BN2) bf16
  float* accbuf = (float*)(ws + 50855936);  // 512 floats: sum1,sq1,sum2,sq2

  u16* wwb = wb + 49152;  u16* wf1b = wb + 65536; u16* wf2b = wb + 131072;

  dim3 blk(256);

  // 1. QKV projections + cvt(Ww,Wf1,Wf2) + zero accbuf   (913 blocks)
  qkv_k<<<dim3(913), blk, 0, stream>>>(node, Wq,bq, Wk,bk, Wv,bv, Ww, Wf1, Wf2,
                                       qb, kb, vb, wb, accbuf);
  // 2. attention
  attn_k<<<dim3(1024), blk, 0, stream>>>(qb, kb, vb, ab);
  // 3. out-proj + node residual -> xb, BN1 sums -> accbuf[0..256)
  oproj_k<<<dim3(256,2), blk, 0, stream>>>(ab, wwb, bw, node, accbuf, xb);
  // 4. fused FFN1+FFN2 (hidden slice in LDS) -> x2b, BN2 sums -> accbuf[256..)
  ffn_k<<<dim3(512), dim3(512), 0, stream>>>(xb, wf1b, bf1, wf2b, bf2,
                                             accbuf, g1, be1, accbuf + 256, x2b);
  // 5. BN2 apply -> fp32 out
  bn_final<<<dim3(512), blk, 0, stream>>>((const uint2*)x2b, accbuf + 256, g2, be2, out);
}

// Round 4
// 200.402 us; speedup vs baseline: 1.0512x; 1.0512x over previous
//
#include <hip/hip_runtime.h>
#include <stdint.h>

typedef unsigned int  uint32;
typedef unsigned short u16;
typedef __attribute__((ext_vector_type(8))) short short8;
typedef __attribute__((ext_vector_type(4))) float f32x4;
typedef __attribute__((ext_vector_type(4))) _Float16 half4;

// ---------- helpers ----------
__device__ __forceinline__ float bits2f(uint32 u){ union{uint32 u; float f;} c; c.u=u; return c.f; }
__device__ __forceinline__ uint32 f2bits(float f){ union{uint32 u; float f;} c; c.f=f; return c.u; }
__device__ __forceinline__ u16 f2b(float f){ uint32 u=f2bits(f); return (u16)((u + 0x7FFFu + ((u>>16)&1u))>>16); }
__device__ __forceinline__ float b2f(u16 h){ return bits2f(((uint32)h)<<16); }
__device__ __forceinline__ u16 f2h(float f){ _Float16 h=(_Float16)f; union{u16 u; _Float16 h;} c; c.h=h; return c.u; }
__device__ __forceinline__ float4 ld4f(const float* p){ return *(const float4*)p; }
#define BLO(u) bits2f((u)<<16)
#define BHI(u) bits2f((u)&0xFFFF0000u)

#define QKS 24

// ---------- fold raw BN sums into per-channel affine in LDS ----------
__device__ __forceinline__ void load_ab(const float* __restrict__ gacc,
                                        const float* __restrict__ gam,
                                        const float* __restrict__ bet,
                                        float* sA, float* sB, int t)
{
  if (t < 128) {
    const float mean = gacc[t] * (1.f/32768.f);
    const float var  = gacc[128 + t] * (1.f/32768.f) - mean * mean;
    const float rstd = rsqrtf(var + 1e-5f);
    const float Ac = gam[t] * rstd;
    sA[t] = Ac;
    sB[t] = bet[t] - mean * Ac;
  }
  __syncthreads();
}

// ---------- GEMM tile: 128 x (JT*32), BK=64, 4 waves, 16x16x32 bf16 MFMA ----------
// OMODE: 0 bf16 row-major | 2 f16 [T][M][N][D] (*oscale) | 3 f16 [T][M][D][N]
// RES: 0 none | 1 f32 stride128 | 3 bf16 stride128 * BN affine (sA/sB)
// AF32: A fp32 convert in staging. WF32: W fp32 convert in staging.
// BNA: BN affine on A channels (K==128, sA/sB). STATS: channel sums -> gacc atomics.
template<int OMODE, int RES, bool RELU, bool AF32, bool WF32, bool BNA, bool STATS, int JT>
__device__ __forceinline__ void gemm_tile(
    u16* As, u16* Ws, const float* sA, const float* sB, float* pS, float* pQ,
    const void* Ain, const void* W, const float* bias, const void* res,
    float* gacc_out, void* out, int row0, int col0, int K, int Nout,
    float oscale, int t)
{
  constexpr int WROWS = JT * 32;
  const int L = t & 63, w = t >> 6;
  const int wrow = (w >> 1) * 64, wcol = (w & 1) * (JT * 16);
  const int lm = L & 15, lg = L >> 4;

  f32x4 acc[4][JT];
#pragma unroll
  for (int i = 0; i < 4; ++i)
#pragma unroll
    for (int j = 0; j < JT; ++j) acc[i][j] = (f32x4){0.f,0.f,0.f,0.f};

  const int srow = t >> 1, skc = (t & 1) * 32;
  const u16*   Ab = (const u16*)Ain + (size_t)(row0 + srow) * K + skc;
  const float* Af = (const float*)Ain + (size_t)(row0 + srow) * K + skc;
  u16* Asp = As + srow * 72 + skc;
  constexpr int TPR = 256 / WROWS;
  const int wsrow = t / TPR, wskc = (t % TPR) * (64 / TPR);
  const u16*   Wp  = (const u16*)W + (size_t)(col0 + wsrow) * K + wskc;
  const float* Wpf = (const float*)W + (size_t)(col0 + wsrow) * K + wskc;
  u16* Wsp = Ws + wsrow * 72 + wskc;
  constexpr int NW = (64 / TPR) / 8;

  // one K-chunk of raw staging data held in registers (in-flight chunk)
  short8 ga[4]; short8 gw[NW];
  float4 fa[4][2]; float4 fw[NW][2];

  auto load_chunk = [&](int k0) {
    if constexpr (AF32) {
#pragma unroll
      for (int i = 0; i < 4; ++i) {
        fa[i][0] = ld4f(Af + k0 + i*8);
        fa[i][1] = ld4f(Af + k0 + i*8 + 4);
      }
    } else {
#pragma unroll
      for (int i = 0; i < 4; ++i) ga[i] = *(const short8*)(Ab + k0 + i*8);
    }
    if constexpr (WF32) {
#pragma unroll
      for (int i = 0; i < NW; ++i) {
        fw[i][0] = ld4f(Wpf + k0 + i*8);
        fw[i][1] = ld4f(Wpf + k0 + i*8 + 4);
      }
    } else {
#pragma unroll
      for (int i = 0; i < NW; ++i) gw[i] = *(const short8*)(Wp + k0 + i*8);
    }
  };

  auto write_chunk = [&](int k0) {
    if constexpr (AF32) {
#pragma unroll
      for (int i = 0; i < 4; ++i) {
        short8 s;
        s[0]=(short)f2b(fa[i][0].x); s[1]=(short)f2b(fa[i][0].y);
        s[2]=(short)f2b(fa[i][0].z); s[3]=(short)f2b(fa[i][0].w);
        s[4]=(short)f2b(fa[i][1].x); s[5]=(short)f2b(fa[i][1].y);
        s[6]=(short)f2b(fa[i][1].z); s[7]=(short)f2b(fa[i][1].w);
        *(short8*)(Asp + i*8) = s;
      }
    } else if constexpr (BNA) {
#pragma unroll
      for (int i = 0; i < 4; ++i) {
        const int c = skc + k0 + i*8;   // channel (K == 128)
        const short8 x8 = ga[i];
        const float4 A0 = *(const float4*)&sA[c], A1 = *(const float4*)&sA[c+4];
        const float4 B0 = *(const float4*)&sB[c], B1 = *(const float4*)&sB[c+4];
        short8 s;
        s[0]=(short)f2b(b2f((u16)x8[0])*A0.x+B0.x); s[1]=(short)f2b(b2f((u16)x8[1])*A0.y+B0.y);
        s[2]=(short)f2b(b2f((u16)x8[2])*A0.z+B0.z); s[3]=(short)f2b(b2f((u16)x8[3])*A0.w+B0.w);
        s[4]=(short)f2b(b2f((u16)x8[4])*A1.x+B1.x); s[5]=(short)f2b(b2f((u16)x8[5])*A1.y+B1.y);
        s[6]=(short)f2b(b2f((u16)x8[6])*A1.z+B1.z); s[7]=(short)f2b(b2f((u16)x8[7])*A1.w+B1.w);
        *(short8*)(Asp + i*8) = s;
      }
    } else {
#pragma unroll
      for (int i = 0; i < 4; ++i) *(short8*)(Asp + i*8) = ga[i];
    }
    if constexpr (WF32) {
#pragma unroll
      for (int i = 0; i < NW; ++i) {
        short8 s;
        s[0]=(short)f2b(fw[i][0].x); s[1]=(short)f2b(fw[i][0].y);
        s[2]=(short)f2b(fw[i][0].z); s[3]=(short)f2b(fw[i][0].w);
        s[4]=(short)f2b(fw[i][1].x); s[5]=(short)f2b(fw[i][1].y);
        s[6]=(short)f2b(fw[i][1].z); s[7]=(short)f2b(fw[i][1].w);
        *(short8*)(Wsp + i*8) = s;
      }
    } else {
#pragma unroll
      for (int i = 0; i < NW; ++i) *(short8*)(Wsp + i*8) = gw[i];
    }
  };

  load_chunk(0);
  for (int k0 = 0; k0 < K; k0 += 64) {
    __syncthreads();   // previous chunk fully consumed
    write_chunk(k0);
    __syncthreads();
    if (k0 + 64 < K) load_chunk(k0 + 64);   // prefetch: hides under MFMA below
#pragma unroll
    for (int ks = 0; ks < 64; ks += 32) {
      short8 af[4], wf[JT];
#pragma unroll
      for (int i = 0; i < 4; ++i)
        af[i] = *(const short8*)(As + (wrow + i*16 + lm) * 72 + ks + lg*8);
#pragma unroll
      for (int j = 0; j < JT; ++j)
        wf[j] = *(const short8*)(Ws + (wcol + j*16 + lm) * 72 + ks + lg*8);
#pragma unroll
      for (int i = 0; i < 4; ++i)
#pragma unroll
        for (int j = 0; j < JT; ++j)
          acc[i][j] = __builtin_amdgcn_mfma_f32_16x16x32_bf16(af[i], wf[j], acc[i][j], 0, 0, 0);
    }
  }

  float bj[JT];
#pragma unroll
  for (int j = 0; j < JT; ++j) bj[j] = bias[col0 + wcol + j*16 + lm];

  float stS[JT], stQ[JT];
#pragma unroll
  for (int j = 0; j < JT; ++j) { stS[j] = 0.f; stQ[j] = 0.f; }

#pragma unroll
  for (int i = 0; i < 4; ++i) {
    const int rowb = row0 + wrow + i*16 + lg*4;
#pragma unroll
    for (int j = 0; j < JT; ++j) {
      const int col = col0 + wcol + j*16 + lm;
      float ra = 0.f, rb = 0.f;
      if constexpr (RES == 3) { ra = sA[col & 127]; rb = sB[col & 127]; }
      if constexpr (OMODE == 3) {   // f16 [T][M][D][N]
        const int tt = rowb >> 8, n0 = rowb & 255;
        const int mh = col >> 4, d = col & 15;
        uint2 o;
        o.x = (uint32)f2h(acc[i][j][0] + bj[j]) | ((uint32)f2h(acc[i][j][1] + bj[j]) << 16);
        o.y = (uint32)f2h(acc[i][j][2] + bj[j]) | ((uint32)f2h(acc[i][j][3] + bj[j]) << 16);
        *(uint2*)((u16*)out + (((size_t)tt*8 + mh)*16 + d)*256 + n0) = o;
      } else {
#pragma unroll
        for (int r = 0; r < 4; ++r) {
          const int row = rowb + r;
          float v = acc[i][j][r] + bj[j];
          if constexpr (RES == 1) v += ((const float*)res)[(size_t)row*128 + col];
          if constexpr (RES == 3) v += b2f(((const u16*)res)[(size_t)row*128 + col]) * ra + rb;
          if constexpr (RELU) v = fmaxf(v, 0.f);
          if constexpr (STATS) { stS[j] += v; stQ[j] += v*v; }
          if constexpr (OMODE == 2) {
            const int tt = row >> 8, n = row & 255, mh = col >> 4, d = col & 15;
            ((u16*)out)[(((size_t)tt*8 + mh)*256 + n)*16 + d] = f2h(v * oscale);
          } else {
            ((u16*)out)[(size_t)row * Nout + col] = f2b(v);
          }
        }
      }
    }
  }

  if constexpr (STATS) {   // Nout == 128
    __syncthreads();
    if (t < 128) { pS[t] = 0.f; pQ[t] = 0.f; }
    __syncthreads();
#pragma unroll
    for (int j = 0; j < JT; ++j) {
      const int col = col0 + wcol + j*16 + lm;
      atomicAdd(&pS[col], stS[j]);
      atomicAdd(&pQ[col], stQ[j]);
    }
    __syncthreads();
    if (t < 128) {
      atomicAdd(&gacc_out[t],       pS[t]);
      atomicAdd(&gacc_out[128 + t], pQ[t]);
    }
  }
}

// ---------- node 1: QKV projections (W fp32 in staging) + cvt(Ww,Wf1,Wf2) + zero accbuf ----------
__global__ __launch_bounds__(256)
void qkv_k(const float* __restrict__ node,
           const float* __restrict__ Wq, const float* __restrict__ bq,
           const float* __restrict__ Wk, const float* __restrict__ bk,
           const float* __restrict__ Wv, const float* __restrict__ bv,
           const float* __restrict__ Ww, const float* __restrict__ Wf1,
           const float* __restrict__ Wf2,
           u16* __restrict__ qb, u16* __restrict__ kb, u16* __restrict__ vb,
           u16* __restrict__ wb, float* __restrict__ accbuf)
{
  const int bid = blockIdx.x, t = threadIdx.x;
  if (bid < 768) {
    __shared__ u16 As[128*72];
    __shared__ u16 Ws[128*72];
    __shared__ __align__(16) float sA[128], sB[128];
    __shared__ float pS[128], pQ[128];
    const int x = bid & 255, y = bid >> 8;
    const float QSCALE = 0.36067376022224085f;  // 0.25 * log2(e)
    if (y == 0)
      gemm_tile<2,0,false,true,true,false,false,4>(As,Ws,sA,sB,pS,pQ, node, Wq, bq,
          nullptr, nullptr, qb, x*128, 0, 128, 128, QSCALE, t);
    else if (y == 1)
      gemm_tile<2,0,false,true,true,false,false,4>(As,Ws,sA,sB,pS,pQ, node, Wk, bk,
          nullptr, nullptr, kb, x*128, 0, 128, 128, 1.f, t);
    else
      gemm_tile<3,0,false,true,true,false,false,4>(As,Ws,sA,sB,pS,pQ, node, Wv, bv,
          nullptr, nullptr, vb, x*128, 0, 128, 128, 1.f, t);
  } else if (bid < 912) {
    // convert Ww/Wf1/Wf2 fp32 -> bf16 into wb (layout: Ww@49152, Wf1@65536, Wf2@131072 u16)
    const int i = (bid - 768) * 256 + t;   // 0..36863 float4
    const float4* src; u16* dst;
    if      (i <  4096) { src = (const float4*)Ww  + i;         dst = wb +  49152 + (size_t)i*4; }
    else if (i < 20480) { src = (const float4*)Wf1 + (i-4096);  dst = wb +  65536 + (size_t)(i-4096)*4; }
    else                { src = (const float4*)Wf2 + (i-20480); dst = wb + 131072 + (size_t)(i-20480)*4; }
    float4 v = *src;
    uint2 o;
    o.x = (uint32)f2b(v.x) | ((uint32)f2b(v.y) << 16);
    o.y = (uint32)f2b(v.z) | ((uint32)f2b(v.w) << 16);
    *(uint2*)dst = o;
  } else {
    accbuf[t] = 0.f;
    accbuf[256 + t] = 0.f;
  }
}

// ---------- out-proj: + node residual, BN1 stats.  128x64 tiles -> 512 blocks ----------
__global__ __launch_bounds__(256)
void oproj_k(const u16* __restrict__ ab, const u16* __restrict__ wwb,
             const float* __restrict__ bw, const float* __restrict__ node,
             float* __restrict__ accbuf, u16* __restrict__ xb)
{
  __shared__ u16 As[128*72];
  __shared__ u16 Ws[64*72];
  __shared__ __align__(16) float sA[128], sB[128];
  __shared__ float pS[128], pQ[128];
  gemm_tile<0,1,false,false,false,false,true,2>(As,Ws,sA,sB,pS,pQ, ab, wwb, bw,
      node, accbuf, xb, blockIdx.x*128, blockIdx.y*64, 128, 128, 1.f, threadIdx.x);
}

// ---------- fused FFN v3: per 64-row slice, hidden processed in 2 halves of 256 ----------
// half h: h-slice = relu(BN1(xb) @ Wf1[h*256..+256]^T + bf1) -> Hs (64x264 LDS, bf16)
//         then accumulate accF2 += h-slice @ Wf2[:, h*256..+256]^T
// LDS ~70 KB -> 2 blocks/CU (vs R3's 102 KB -> 1/CU, measured Occupancy 16%, MfmaUtil 6%).
// Numerics identical to R3 fused (same k order 0..511, same bf16 quantization of h).
#define HS2_LD 264  // 64 x 264 u16
#define AS_LD 136   // 64 x 136 u16
#define WS_LD 72    // 128 x 72 u16

__global__ __launch_bounds__(512, 4)
void ffn_k(const u16* __restrict__ xb, const u16* __restrict__ wf1b,
           const float* __restrict__ bf1, const u16* __restrict__ wf2b,
           const float* __restrict__ bf2, const float* __restrict__ accbuf,
           const float* __restrict__ g1, const float* __restrict__ be1,
           float* __restrict__ acc2, u16* __restrict__ x2b)
{
  __shared__ u16 Hs[64*HS2_LD];
  __shared__ u16 As[64*AS_LD];
  __shared__ u16 Ws[128*WS_LD];
  __shared__ __align__(16) float sA[128], sB[128];
  __shared__ float pS[128], pQ[128];

  const int t = threadIdx.x;
  const int row0 = blockIdx.x * 64;
  load_ab(accbuf, g1, be1, sA, sB, t);   // BN1 affine (includes __syncthreads)

  // ---- stage A = BN1(xb[row0 .. row0+64][0:128]) into As, once ----
  {
    const int r = t >> 3, seg = (t & 7) * 16;   // 16 values / thread
    const u16* src = xb + (size_t)(row0 + r) * 128 + seg;
    u16* dst = As + r * AS_LD + seg;
#pragma unroll
    for (int h = 0; h < 2; ++h) {
      const short8 x8 = *(const short8*)(src + h*8);
      const int c = seg + h*8;
      const float4 A0 = *(const float4*)&sA[c], A1 = *(const float4*)&sA[c+4];
      const float4 B0 = *(const float4*)&sB[c], B1 = *(const float4*)&sB[c+4];
      short8 s;
      s[0]=(short)f2b(b2f((u16)x8[0])*A0.x+B0.x); s[1]=(short)f2b(b2f((u16)x8[1])*A0.y+B0.y);
      s[2]=(short)f2b(b2f((u16)x8[2])*A0.z+B0.z); s[3]=(short)f2b(b2f((u16)x8[3])*A0.w+B0.w);
      s[4]=(short)f2b(b2f((u16)x8[4])*A1.x+B1.x); s[5]=(short)f2b(b2f((u16)x8[5])*A1.y+B1.y);
      s[6]=(short)f2b(b2f((u16)x8[6])*A1.z+B1.z); s[7]=(short)f2b(b2f((u16)x8[7])*A1.w+B1.w);
      *(short8*)(dst + h*8) = s;
    }
  }

  const int w = t >> 6, L = t & 63, lm = L & 15, lg = L >> 4;
  const int wcol = w * 16;            // 8 waves x 16 cols = 128 output cols
  const int wr = t >> 2, kc = (t & 3) * 16;   // W staging: 128 rows x 64 k / 512 thr

  // global chunk g in [0,16): half = g>>3, cc = g&7.
  // cc<4 -> ffn1 W chunk: hidden tile ct = 2*half + (cc>>1), k0 = (cc&1)*64
  // cc>=4 -> ffn2 W chunk: k window = half*256 + (cc-4)*64
  auto wsrc = [&](int g) -> const u16* {
    const int half = g >> 3, cc = g & 7;
    if (cc < 4) return wf1b + (size_t)((2*half + (cc>>1))*128 + wr)*128 + (cc&1)*64 + kc;
    return wf2b + (size_t)wr*512 + half*256 + (cc-4)*64 + kc;
  };

  f32x4 accF[4];   // ffn1 accumulator (reset per hidden col-tile)
  f32x4 acc2r[4];  // ffn2 accumulator (persists across both halves)
#pragma unroll
  for (int i = 0; i < 4; ++i) {
    accF[i]  = (f32x4){0.f,0.f,0.f,0.f};
    acc2r[i] = (f32x4){0.f,0.f,0.f,0.f};
  }

  short8 gw0 = *(const short8*)(wsrc(0));
  short8 gw1 = *(const short8*)(wsrc(0) + 8);

  for (int g = 0; g < 16; ++g) {
    const int cc = g & 7;
    const bool is1 = (cc < 4);
    __syncthreads();                       // Ws (and As/Hs writes) consumed/visible
    *(short8*)(Ws + wr*WS_LD + kc)     = gw0;
    *(short8*)(Ws + wr*WS_LD + kc + 8) = gw1;
    __syncthreads();
    if (g < 15) {                          // prefetch next W chunk
      gw0 = *(const short8*)(wsrc(g+1));
      gw1 = *(const short8*)(wsrc(g+1) + 8);
    }
    const u16* Abase = is1 ? (As + ((size_t)(cc & 1) * 64))
                           : (Hs + ((size_t)(cc - 4) * 64));
    const int ald = is1 ? AS_LD : HS2_LD;
#pragma unroll
    for (int ks = 0; ks < 64; ks += 32) {
      short8 af[4], wf;
#pragma unroll
      for (int i = 0; i < 4; ++i)
        af[i] = *(const short8*)(Abase + (i*16 + lm) * ald + ks + lg*8);
      wf = *(const short8*)(Ws + (wcol + lm) * WS_LD + ks + lg*8);
      if (is1) {
#pragma unroll
        for (int i = 0; i < 4; ++i)
          accF[i] = __builtin_amdgcn_mfma_f32_16x16x32_bf16(af[i], wf, accF[i], 0, 0, 0);
      } else {
#pragma unroll
        for (int i = 0; i < 4; ++i)
          acc2r[i] = __builtin_amdgcn_mfma_f32_16x16x32_bf16(af[i], wf, acc2r[i], 0, 0, 0);
      }
    }
    if (is1 && (cc & 1)) {                 // ffn1 col-tile done -> relu+bias -> Hs
      const int half = g >> 3;
      const int ct = 2*half + (cc >> 1);   // global hidden tile
      const int lct = cc >> 1;             // local tile within this half (0/1)
      const float b1 = bf1[ct*128 + wcol + lm];
#pragma unroll
      for (int i = 0; i < 4; ++i) {
#pragma unroll
        for (int r = 0; r < 4; ++r) {
          const int row = i*16 + lg*4 + r;
          Hs[row*HS2_LD + lct*128 + wcol + lm] = f2b(fmaxf(accF[i][r] + b1, 0.f));
        }
        accF[i] = (f32x4){0.f,0.f,0.f,0.f};
      }
    }
  }

  // ---- ffn2 epilogue: + BN1(xb) residual, BN2 stats, store x2b ----
  const int col = wcol + lm;
  const float b2 = bf2[col];
  const float ra = sA[col], rb = sB[col];
  float stS = 0.f, stQ = 0.f;
#pragma unroll
  for (int i = 0; i < 4; ++i) {
#pragma unroll
    for (int r = 0; r < 4; ++r) {
      const int row = row0 + i*16 + lg*4 + r;
      float v = acc2r[i][r] + b2 + b2f(xb[(size_t)row*128 + col]) * ra + rb;
      stS += v; stQ += v*v;
      x2b[(size_t)row*128 + col] = f2b(v);
    }
  }
  __syncthreads();
  if (t < 128) { pS[t] = 0.f; pQ[t] = 0.f; }
  __syncthreads();
  atomicAdd(&pS[col], stS);
  atomicAdd(&pQ[col], stQ);
  __syncthreads();
  if (t < 128) {
    atomicAdd(&acc2[t],       pS[t]);
    atomicAdd(&acc2[128 + t], pQ[t]);
  }
}

// ---------- attention: 1 block per (t,m), 4 waves, f16 16x16x16 MFMA ----------
__global__ __launch_bounds__(256)
void attn_k(const u16* __restrict__ q, const u16* __restrict__ k,
            const u16* __restrict__ v, u16* __restrict__ ab)
{
  __shared__ __align__(16) u16 Qs[256*QKS];
  __shared__ __align__(16) u16 Ks[256*QKS];
  __shared__ __align__(16) u16 Vt[16*264];
  const int tm = blockIdx.x, tt = tm >> 3, m = tm & 7;
  const int t = threadIdx.x;

  const uint4* qg = (const uint4*)(q + (size_t)tm*4096);
  const uint4* kg = (const uint4*)(k + (size_t)tm*4096);
  const uint4* vg = (const uint4*)(v + (size_t)tm*4096);
#pragma unroll
  for (int p = t; p < 512; p += 256) {
    const uint4 a = qg[p], b = kg[p], c = vg[p];
    const int row = p >> 1, h = (p & 1) * 8;
    *(uint4*)(Qs + row*QKS + h) = a;
    *(uint4*)(Ks + row*QKS + h) = b;
    *(uint4*)(Vt + (p >> 5)*264 + (p & 31)*8) = c;
  }
  __syncthreads();

  const int w = t >> 6, L = t & 63, lm = L & 15, quad = L >> 4;

  half4 vf[16];
#pragma unroll
  for (int jt = 0; jt < 16; ++jt)
    vf[jt] = *(const half4*)(Vt + lm*264 + jt*16 + quad*4);

  for (int nt = 0; nt < 4; ++nt) {
    const half4 bq = *(const half4*)(Qs + ((w*4 + nt)*16 + lm)*QKS + quad*4);
    f32x4 s[16];
#pragma unroll
    for (int jt = 0; jt < 16; ++jt) {
      const half4 af = *(const half4*)(Ks + (jt*16 + lm)*QKS + quad*4);
      s[jt] = __builtin_amdgcn_mfma_f32_16x16x16f16(af, bq, (f32x4){0.f,0.f,0.f,0.f}, 0, 0, 0);
    }
    float mx = s[0][0];
#pragma unroll
    for (int jt = 0; jt < 16; ++jt)
#pragma unroll
      for (int r = 0; r < 4; ++r) mx = fmaxf(mx, s[jt][r]);
    mx = fmaxf(mx, __shfl_xor(mx, 16));
    mx = fmaxf(mx, __shfl_xor(mx, 32));
    float ls = 0.f;
#pragma unroll
    for (int jt = 0; jt < 16; ++jt)
#pragma unroll
      for (int r = 0; r < 4; ++r) { const float p = exp2f(s[jt][r] - mx); s[jt][r] = p; ls += p; }
    ls += __shfl_xor(ls, 16);
    ls += __shfl_xor(ls, 32);

    f32x4 oacc = {0.f,0.f,0.f,0.f};
#pragma unroll
    for (int jt = 0; jt < 16; ++jt) {
      half4 pf;
      pf[0] = (_Float16)s[jt][0]; pf[1] = (_Float16)s[jt][1];
      pf[2] = (_Float16)s[jt][2]; pf[3] = (_Float16)s[jt][3];
      oacc = __builtin_amdgcn_mfma_f32_16x16x16f16(pf, vf[jt], oacc, 0, 0, 0);
    }
    const int q0 = w*64 + nt*16 + quad*4;
#pragma unroll
    for (int r = 0; r < 4; ++r) {
      const float lr = __shfl(ls, quad*4 + r);
      ab[((size_t)tt*256 + q0 + r)*128 + m*16 + lm] = f2b(oacc[r] / lr);
    }
  }
}

// ---------- final: BN2 affine + apply bf16 -> fp32 out (512 blocks, uint2 loads) ----------
__global__ __launch_bounds__(256)
void bn_final(const uint2* __restrict__ x2, const float* __restrict__ gacc,
              const float* __restrict__ gam, const float* __restrict__ bet,
              float* __restrict__ out)
{
  __shared__ __align__(16) float sA[128], sB[128];
  const int t = threadIdx.x;
  load_ab(gacc, gam, bet, sA, sB, t);
#pragma unroll 2
  for (int kk = 0; kk < 8; ++kk) {
    const size_t idx = (size_t)blockIdx.x * 2048 + kk * 256 + t;
    const uint2 u = x2[idx];
    const int c = (int)((idx & 31) * 4);   // 4 consecutive channels, 16B aligned
    const f32x4 A = *(const f32x4*)&sA[c];
    const f32x4 B = *(const f32x4*)&sB[c];
    f32x4 o;
    o[0] = BLO(u.x)*A[0] + B[0];
    o[1] = BHI(u.x)*A[1] + B[1];
    o[2] = BLO(u.y)*A[2] + B[2];
    o[3] = BHI(u.y)*A[3] + B[3];
    *(f32x4*)(out + idx*4) = o;
  }
}

// ---------- launch: 5 nodes ----------
extern "C" void kernel_launch(void* const* d_in, const int* in_sizes, int n_in,
                              void* d_out, int out_size, void* d_ws, size_t ws_size,
                              hipStream_t stream)
{
  (void)in_sizes; (void)n_in; (void)out_size; (void)ws_size;
  const float* node = (const float*)d_in[0];
  const float* Wq  = (const float*)d_in[1];  const float* bq  = (const float*)d_in[2];
  const float* Wk  = (const float*)d_in[3];  const float* bk  = (const float*)d_in[4];
  const float* Wv  = (const float*)d_in[5];  const float* bv  = (const float*)d_in[6];
  const float* Ww  = (const float*)d_in[7];  const float* bw  = (const float*)d_in[8];
  const float* Wf1 = (const float*)d_in[9];  const float* bf1 = (const float*)d_in[10];
  const float* Wf2 = (const float*)d_in[11]; const float* bf2 = (const float*)d_in[12];
  const float* g1  = (const float*)d_in[13]; const float* be1 = (const float*)d_in[14];
  const float* g2  = (const float*)d_in[15]; const float* be2 = (const float*)d_in[16];
  float* out = (float*)d_out;
  char* ws = (char*)d_ws;

  // workspace (bytes)
  u16* wb  = (u16*)(ws + 0);          // weights bf16 concat (Ww@49152, Wf1@65536, Wf2@131072 u16)
  u16* qb  = (u16*)(ws + 524288);     // q f16 [T][M][N][D] (pre-scaled)
  u16* kb  = (u16*)(ws + 8912896);    // k f16 [T][M][N][D]
  u16* vb  = (u16*)(ws + 17301504);   // v f16 [T][M][D][N]
  u16* ab  = (u16*)(ws + 25690112);   // attn out bf16 [T][N][E]
  u16* xb  = (u16*)(ws + 34078720);   // x (pre-BN1) bf16
  u16* x2b = (u16*)(ws + 42467328);   // x2 (pre-BN2) bf16
  float* accbuf = (float*)(ws + 50855936);  // 512 floats: sum1,sq1,sum2,sq2

  u16* wwb = wb + 49152;  u16* wf1b = wb + 65536; u16* wf2b = wb + 131072;

  dim3 blk(256);

  // 1. QKV projections + cvt(Ww,Wf1,Wf2) + zero accbuf   (913 blocks)
  qkv_k<<<dim3(913), blk, 0, stream>>>(node, Wq,bq, Wk,bk, Wv,bv, Ww, Wf1, Wf2,
                                       qb, kb, vb, wb, accbuf);
  // 2. attention
  attn_k<<<dim3(1024), blk, 0, stream>>>(qb, kb, vb, ab);
  // 3. out-proj + node residual -> xb, BN1 sums -> accbuf[0..256)
  oproj_k<<<dim3(256,2), blk, 0, stream>>>(ab, wwb, bw, node, accbuf, xb);
  // 4. fused FFN1+FFN2 v3 (2-half hidden in LDS, 2 blocks/CU) -> x2b, BN2 sums
  ffn_k<<<dim3(512), dim3(512), 0, stream>>>(xb, wf1b, bf1, wf2b, bf2,
                                             accbuf, g1, be1, accbuf + 256, x2b);
  // 5. BN2 apply -> fp32 out
  bn_final<<<dim3(512), blk, 0, stream>>>((const uint2*)x2b, accbuf + 256, g2, be2, out);
}

// Round 5
// 200.095 us; speedup vs baseline: 1.0528x; 1.0015x over previous
//
#include <hip/hip_runtime.h>
#include <stdint.h>

typedef unsigned int  uint32;
typedef unsigned short u16;
typedef __attribute__((ext_vector_type(8))) short short8;
typedef __attribute__((ext_vector_type(4))) float f32x4;
typedef __attribute__((ext_vector_type(4))) _Float16 half4;

// ---------- helpers ----------
__device__ __forceinline__ float bits2f(uint32 u){ union{uint32 u; float f;} c; c.u=u; return c.f; }
__device__ __forceinline__ uint32 f2bits(float f){ union{uint32 u; float f;} c; c.f=f; return c.u; }
__device__ __forceinline__ u16 f2b(float f){ uint32 u=f2bits(f); return (u16)((u + 0x7FFFu + ((u>>16)&1u))>>16); }
__device__ __forceinline__ float b2f(u16 h){ return bits2f(((uint32)h)<<16); }
__device__ __forceinline__ u16 f2h(float f){ _Float16 h=(_Float16)f; union{u16 u; _Float16 h;} c; c.h=h; return c.u; }
__device__ __forceinline__ float4 ld4f(const float* p){ return *(const float4*)p; }
#define BLO(u) bits2f((u)<<16)
#define BHI(u) bits2f((u)&0xFFFF0000u)

#define QKS 24

// ---------- fold raw BN sums into per-channel affine in LDS ----------
__device__ __forceinline__ void load_ab(const float* __restrict__ gacc,
                                        const float* __restrict__ gam,
                                        const float* __restrict__ bet,
                                        float* sA, float* sB, int t)
{
  if (t < 128) {
    const float mean = gacc[t] * (1.f/32768.f);
    const float var  = gacc[128 + t] * (1.f/32768.f) - mean * mean;
    const float rstd = rsqrtf(var + 1e-5f);
    const float Ac = gam[t] * rstd;
    sA[t] = Ac;
    sB[t] = bet[t] - mean * Ac;
  }
  __syncthreads();
}

// ---------- GEMM tile: 128 x (JT*32), BK=64, 4 waves, 16x16x32 bf16 MFMA ----------
// OMODE: 0 bf16 row-major | 2 f16 [T][M][N][D] (*oscale) | 3 f16 [T][M][D][N]
// RES: 0 none | 1 f32 stride128 | 3 bf16 stride128 * BN affine (sA/sB)
// AF32: A fp32 convert in staging. WF32: W fp32 convert in staging.
// BNA: BN affine on A channels (K==128, sA/sB). STATS: channel sums -> gacc atomics.
template<int OMODE, int RES, bool RELU, bool AF32, bool WF32, bool BNA, bool STATS, int JT>
__device__ __forceinline__ void gemm_tile(
    u16* As, u16* Ws, const float* sA, const float* sB, float* pS, float* pQ,
    const void* Ain, const void* W, const float* bias, const void* res,
    float* gacc_out, void* out, int row0, int col0, int K, int Nout,
    float oscale, int t)
{
  constexpr int WROWS = JT * 32;
  const int L = t & 63, w = t >> 6;
  const int wrow = (w >> 1) * 64, wcol = (w & 1) * (JT * 16);
  const int lm = L & 15, lg = L >> 4;

  f32x4 acc[4][JT];
#pragma unroll
  for (int i = 0; i < 4; ++i)
#pragma unroll
    for (int j = 0; j < JT; ++j) acc[i][j] = (f32x4){0.f,0.f,0.f,0.f};

  const int srow = t >> 1, skc = (t & 1) * 32;
  const u16*   Ab = (const u16*)Ain + (size_t)(row0 + srow) * K + skc;
  const float* Af = (const float*)Ain + (size_t)(row0 + srow) * K + skc;
  u16* Asp = As + srow * 72 + skc;
  constexpr int TPR = 256 / WROWS;
  const int wsrow = t / TPR, wskc = (t % TPR) * (64 / TPR);
  const u16*   Wp  = (const u16*)W + (size_t)(col0 + wsrow) * K + wskc;
  const float* Wpf = (const float*)W + (size_t)(col0 + wsrow) * K + wskc;
  u16* Wsp = Ws + wsrow * 72 + wskc;
  constexpr int NW = (64 / TPR) / 8;

  // one K-chunk of raw staging data held in registers (in-flight chunk)
  short8 ga[4]; short8 gw[NW];
  float4 fa[4][2]; float4 fw[NW][2];

  auto load_chunk = [&](int k0) {
    if constexpr (AF32) {
#pragma unroll
      for (int i = 0; i < 4; ++i) {
        fa[i][0] = ld4f(Af + k0 + i*8);
        fa[i][1] = ld4f(Af + k0 + i*8 + 4);
      }
    } else {
#pragma unroll
      for (int i = 0; i < 4; ++i) ga[i] = *(const short8*)(Ab + k0 + i*8);
    }
    if constexpr (WF32) {
#pragma unroll
      for (int i = 0; i < NW; ++i) {
        fw[i][0] = ld4f(Wpf + k0 + i*8);
        fw[i][1] = ld4f(Wpf + k0 + i*8 + 4);
      }
    } else {
#pragma unroll
      for (int i = 0; i < NW; ++i) gw[i] = *(const short8*)(Wp + k0 + i*8);
    }
  };

  auto write_chunk = [&](int k0) {
    if constexpr (AF32) {
#pragma unroll
      for (int i = 0; i < 4; ++i) {
        short8 s;
        s[0]=(short)f2b(fa[i][0].x); s[1]=(short)f2b(fa[i][0].y);
        s[2]=(short)f2b(fa[i][0].z); s[3]=(short)f2b(fa[i][0].w);
        s[4]=(short)f2b(fa[i][1].x); s[5]=(short)f2b(fa[i][1].y);
        s[6]=(short)f2b(fa[i][1].z); s[7]=(short)f2b(fa[i][1].w);
        *(short8*)(Asp + i*8) = s;
      }
    } else if constexpr (BNA) {
#pragma unroll
      for (int i = 0; i < 4; ++i) {
        const int c = skc + k0 + i*8;   // channel (K == 128)
        const short8 x8 = ga[i];
        const float4 A0 = *(const float4*)&sA[c], A1 = *(const float4*)&sA[c+4];
        const float4 B0 = *(const float4*)&sB[c], B1 = *(const float4*)&sB[c+4];
        short8 s;
        s[0]=(short)f2b(b2f((u16)x8[0])*A0.x+B0.x); s[1]=(short)f2b(b2f((u16)x8[1])*A0.y+B0.y);
        s[2]=(short)f2b(b2f((u16)x8[2])*A0.z+B0.z); s[3]=(short)f2b(b2f((u16)x8[3])*A0.w+B0.w);
        s[4]=(short)f2b(b2f((u16)x8[4])*A1.x+B1.x); s[5]=(short)f2b(b2f((u16)x8[5])*A1.y+B1.y);
        s[6]=(short)f2b(b2f((u16)x8[6])*A1.z+B1.z); s[7]=(short)f2b(b2f((u16)x8[7])*A1.w+B1.w);
        *(short8*)(Asp + i*8) = s;
      }
    } else {
#pragma unroll
      for (int i = 0; i < 4; ++i) *(short8*)(Asp + i*8) = ga[i];
    }
    if constexpr (WF32) {
#pragma unroll
      for (int i = 0; i < NW; ++i) {
        short8 s;
        s[0]=(short)f2b(fw[i][0].x); s[1]=(short)f2b(fw[i][0].y);
        s[2]=(short)f2b(fw[i][0].z); s[3]=(short)f2b(fw[i][0].w);
        s[4]=(short)f2b(fw[i][1].x); s[5]=(short)f2b(fw[i][1].y);
        s[6]=(short)f2b(fw[i][1].z); s[7]=(short)f2b(fw[i][1].w);
        *(short8*)(Wsp + i*8) = s;
      }
    } else {
#pragma unroll
      for (int i = 0; i < NW; ++i) *(short8*)(Wsp + i*8) = gw[i];
    }
  };

  load_chunk(0);
  for (int k0 = 0; k0 < K; k0 += 64) {
    __syncthreads();   // previous chunk fully consumed
    write_chunk(k0);
    __syncthreads();
    if (k0 + 64 < K) load_chunk(k0 + 64);   // prefetch: hides under MFMA below
#pragma unroll
    for (int ks = 0; ks < 64; ks += 32) {
      short8 af[4], wf[JT];
#pragma unroll
      for (int i = 0; i < 4; ++i)
        af[i] = *(const short8*)(As + (wrow + i*16 + lm) * 72 + ks + lg*8);
#pragma unroll
      for (int j = 0; j < JT; ++j)
        wf[j] = *(const short8*)(Ws + (wcol + j*16 + lm) * 72 + ks + lg*8);
#pragma unroll
      for (int i = 0; i < 4; ++i)
#pragma unroll
        for (int j = 0; j < JT; ++j)
          acc[i][j] = __builtin_amdgcn_mfma_f32_16x16x32_bf16(af[i], wf[j], acc[i][j], 0, 0, 0);
    }
  }

  float bj[JT];
#pragma unroll
  for (int j = 0; j < JT; ++j) bj[j] = bias[col0 + wcol + j*16 + lm];

  float stS[JT], stQ[JT];
#pragma unroll
  for (int j = 0; j < JT; ++j) { stS[j] = 0.f; stQ[j] = 0.f; }

#pragma unroll
  for (int i = 0; i < 4; ++i) {
    const int rowb = row0 + wrow + i*16 + lg*4;
#pragma unroll
    for (int j = 0; j < JT; ++j) {
      const int col = col0 + wcol + j*16 + lm;
      float ra = 0.f, rb = 0.f;
      if constexpr (RES == 3) { ra = sA[col & 127]; rb = sB[col & 127]; }
      if constexpr (OMODE == 3) {   // f16 [T][M][D][N]
        const int tt = rowb >> 8, n0 = rowb & 255;
        const int mh = col >> 4, d = col & 15;
        uint2 o;
        o.x = (uint32)f2h(acc[i][j][0] + bj[j]) | ((uint32)f2h(acc[i][j][1] + bj[j]) << 16);
        o.y = (uint32)f2h(acc[i][j][2] + bj[j]) | ((uint32)f2h(acc[i][j][3] + bj[j]) << 16);
        *(uint2*)((u16*)out + (((size_t)tt*8 + mh)*16 + d)*256 + n0) = o;
      } else {
#pragma unroll
        for (int r = 0; r < 4; ++r) {
          const int row = rowb + r;
          float v = acc[i][j][r] + bj[j];
          if constexpr (RES == 1) v += ((const float*)res)[(size_t)row*128 + col];
          if constexpr (RES == 3) v += b2f(((const u16*)res)[(size_t)row*128 + col]) * ra + rb;
          if constexpr (RELU) v = fmaxf(v, 0.f);
          if constexpr (STATS) { stS[j] += v; stQ[j] += v*v; }
          if constexpr (OMODE == 2) {
            const int tt = row >> 8, n = row & 255, mh = col >> 4, d = col & 15;
            ((u16*)out)[(((size_t)tt*8 + mh)*256 + n)*16 + d] = f2h(v * oscale);
          } else {
            ((u16*)out)[(size_t)row * Nout + col] = f2b(v);
          }
        }
      }
    }
  }

  if constexpr (STATS) {   // Nout == 128
    __syncthreads();
    if (t < 128) { pS[t] = 0.f; pQ[t] = 0.f; }
    __syncthreads();
#pragma unroll
    for (int j = 0; j < JT; ++j) {
      const int col = col0 + wcol + j*16 + lm;
      atomicAdd(&pS[col], stS[j]);
      atomicAdd(&pQ[col], stQ[j]);
    }
    __syncthreads();
    if (t < 128) {
      atomicAdd(&gacc_out[t],       pS[t]);
      atomicAdd(&gacc_out[128 + t], pQ[t]);
    }
  }
}

// ---------- node 1 (fused): Q,K,V in one block per 128-row tile ----------
// A (node tile, fp32->bf16) staged ONCE into As[2 chunks]; 6 W-phases
// (3 weights x 2 K-chunks) through double-buffered Ws -> 1 barrier/phase.
// Epilogues identical to the old per-y template instantiations.
__global__ __launch_bounds__(256)
void qkv_k(const float* __restrict__ node,
           const float* __restrict__ Wq, const float* __restrict__ bq,
           const float* __restrict__ Wk, const float* __restrict__ bk,
           const float* __restrict__ Wv, const float* __restrict__ bv,
           const float* __restrict__ Ww, const float* __restrict__ Wf1,
           const float* __restrict__ Wf2,
           u16* __restrict__ qb, u16* __restrict__ kb, u16* __restrict__ vb,
           u16* __restrict__ wb, float* __restrict__ accbuf)
{
  const int bid = blockIdx.x, t = threadIdx.x;
  if (bid < 256) {
    __shared__ u16 As[2*128*72];
    __shared__ u16 Ws[2*128*72];
    const int row0 = bid * 128;
    const int L = t & 63, w = t >> 6;
    const int wrow = (w >> 1) * 64, wcol = (w & 1) * 64;
    const int lm = L & 15, lg = L >> 4;
    const int srow = t >> 1, skc = (t & 1) * 32;   // staging: row, 32-k segment

    // ---- stage A = node[row0..+128][0:128] fp32->bf16, both 64-k chunks ----
    {
      const float* Af = node + (size_t)(row0 + srow) * 128 + skc;
#pragma unroll
      for (int c = 0; c < 2; ++c) {
        u16* Asp = As + c*128*72 + srow*72 + skc;
#pragma unroll
        for (int i = 0; i < 4; ++i) {
          const float4 fa = ld4f(Af + c*64 + i*8);
          const float4 fb = ld4f(Af + c*64 + i*8 + 4);
          short8 s;
          s[0]=(short)f2b(fa.x); s[1]=(short)f2b(fa.y); s[2]=(short)f2b(fa.z); s[3]=(short)f2b(fa.w);
          s[4]=(short)f2b(fb.x); s[5]=(short)f2b(fb.y); s[6]=(short)f2b(fb.z); s[7]=(short)f2b(fb.w);
          *(short8*)(Asp + i*8) = s;
        }
      }
    }

    const float* WY0 = Wq; const float* WY1 = Wk; const float* WY2 = Wv;
    float4 fw[4][2];
    {
      const float* Wp = WY0 + (size_t)srow*128 + skc;   // phase 0 prefetch
#pragma unroll
      for (int i = 0; i < 4; ++i) { fw[i][0] = ld4f(Wp + i*8); fw[i][1] = ld4f(Wp + i*8 + 4); }
    }

    f32x4 acc[4][4];
#pragma unroll
    for (int i = 0; i < 4; ++i)
#pragma unroll
      for (int j = 0; j < 4; ++j) acc[i][j] = (f32x4){0.f,0.f,0.f,0.f};

    for (int g = 0; g < 6; ++g) {       // g: y = g>>1 in {q,k,v}, chunk = g&1
      u16* Wsp = Ws + (g&1)*128*72 + srow*72 + skc;
#pragma unroll
      for (int i = 0; i < 4; ++i) {
        short8 s;
        s[0]=(short)f2b(fw[i][0].x); s[1]=(short)f2b(fw[i][0].y);
        s[2]=(short)f2b(fw[i][0].z); s[3]=(short)f2b(fw[i][0].w);
        s[4]=(short)f2b(fw[i][1].x); s[5]=(short)f2b(fw[i][1].y);
        s[6]=(short)f2b(fw[i][1].z); s[7]=(short)f2b(fw[i][1].w);
        *(short8*)(Wsp + i*8) = s;
      }
      __syncthreads();                  // Ws[g&1] + (phase0: As) visible; prior reads of Ws[g&1] retired
      if (g < 5) {                      // prefetch next phase's W chunk
        const int gn = g + 1;
        const float* WYn = (gn < 2) ? WY0 : (gn < 4) ? WY1 : WY2;
        const float* Wp = WYn + (size_t)srow*128 + (gn & 1)*64 + skc;
#pragma unroll
        for (int i = 0; i < 4; ++i) { fw[i][0] = ld4f(Wp + i*8); fw[i][1] = ld4f(Wp + i*8 + 4); }
      }
      const u16* Ab = As + (g&1)*128*72;
      const u16* Wb = Ws + (g&1)*128*72;
#pragma unroll
      for (int ks = 0; ks < 64; ks += 32) {
        short8 af[4], wf[4];
#pragma unroll
        for (int i = 0; i < 4; ++i)
          af[i] = *(const short8*)(Ab + (wrow + i*16 + lm) * 72 + ks + lg*8);
#pragma unroll
        for (int j = 0; j < 4; ++j)
          wf[j] = *(const short8*)(Wb + (wcol + j*16 + lm) * 72 + ks + lg*8);
#pragma unroll
        for (int i = 0; i < 4; ++i)
#pragma unroll
          for (int j = 0; j < 4; ++j)
            acc[i][j] = __builtin_amdgcn_mfma_f32_16x16x32_bf16(af[i], wf[j], acc[i][j], 0, 0, 0);
      }
      if (g & 1) {                      // y finished (both chunks) -> epilogue
        const int y = g >> 1;
        const float* bias = (y == 0) ? bq : (y == 1) ? bk : bv;
        u16* outp = (y == 0) ? qb : (y == 1) ? kb : vb;
        const float osc = (y == 0) ? 0.36067376022224085f : 1.f;  // 0.25*log2(e)
        float bj[4];
#pragma unroll
        for (int j = 0; j < 4; ++j) bj[j] = bias[wcol + j*16 + lm];
        if (y < 2) {                    // f16 [T][M][N][D] (*osc)
#pragma unroll
          for (int i = 0; i < 4; ++i) {
            const int rowb = row0 + wrow + i*16 + lg*4;
#pragma unroll
            for (int j = 0; j < 4; ++j) {
              const int col = wcol + j*16 + lm;
              const int mh = col >> 4, d = col & 15;
#pragma unroll
              for (int r = 0; r < 4; ++r) {
                const int row = rowb + r;
                const int tt2 = row >> 8, n = row & 255;
                outp[(((size_t)tt2*8 + mh)*256 + n)*16 + d] = f2h((acc[i][j][r] + bj[j]) * osc);
              }
            }
          }
        } else {                        // f16 [T][M][D][N]
#pragma unroll
          for (int i = 0; i < 4; ++i) {
            const int rowb = row0 + wrow + i*16 + lg*4;
            const int tt2 = rowb >> 8, n0 = rowb & 255;
#pragma unroll
            for (int j = 0; j < 4; ++j) {
              const int col = wcol + j*16 + lm;
              const int mh = col >> 4, d = col & 15;
              uint2 o;
              o.x = (uint32)f2h(acc[i][j][0] + bj[j]) | ((uint32)f2h(acc[i][j][1] + bj[j]) << 16);
              o.y = (uint32)f2h(acc[i][j][2] + bj[j]) | ((uint32)f2h(acc[i][j][3] + bj[j]) << 16);
              *(uint2*)(outp + (((size_t)tt2*8 + mh)*16 + d)*256 + n0) = o;
            }
          }
        }
#pragma unroll
        for (int i = 0; i < 4; ++i)
#pragma unroll
          for (int j = 0; j < 4; ++j) acc[i][j] = (f32x4){0.f,0.f,0.f,0.f};
      }
    }
  } else if (bid < 400) {
    // convert Ww/Wf1/Wf2 fp32 -> bf16 into wb (layout: Ww@49152, Wf1@65536, Wf2@131072 u16)
    const int i = (bid - 256) * 256 + t;   // 0..36863 float4
    const float4* src; u16* dst;
    if      (i <  4096) { src = (const float4*)Ww  + i;         dst = wb +  49152 + (size_t)i*4; }
    else if (i < 20480) { src = (const float4*)Wf1 + (i-4096);  dst = wb +  65536 + (size_t)(i-4096)*4; }
    else                { src = (const float4*)Wf2 + (i-20480); dst = wb + 131072 + (size_t)(i-20480)*4; }
    float4 v = *src;
    uint2 o;
    o.x = (uint32)f2b(v.x) | ((uint32)f2b(v.y) << 16);
    o.y = (uint32)f2b(v.z) | ((uint32)f2b(v.w) << 16);
    *(uint2*)dst = o;
  } else {
    accbuf[t] = 0.f;
    accbuf[256 + t] = 0.f;
  }
}

// ---------- out-proj: + node residual, BN1 stats.  128x64 tiles -> 512 blocks ----------
__global__ __launch_bounds__(256)
void oproj_k(const u16* __restrict__ ab, const u16* __restrict__ wwb,
             const float* __restrict__ bw, const float* __restrict__ node,
             float* __restrict__ accbuf, u16* __restrict__ xb)
{
  __shared__ u16 As[128*72];
  __shared__ u16 Ws[64*72];
  __shared__ __align__(16) float sA[128], sB[128];
  __shared__ float pS[128], pQ[128];
  gemm_tile<0,1,false,false,false,false,true,2>(As,Ws,sA,sB,pS,pQ, ab, wwb, bw,
      node, accbuf, xb, blockIdx.x*128, blockIdx.y*64, 128, 128, 1.f, threadIdx.x);
}

// ---------- fused FFN v3: per 64-row slice, hidden processed in 2 halves of 256 ----------
// half h: h-slice = relu(BN1(xb) @ Wf1[h*256..+256]^T + bf1) -> Hs (64x264 LDS, bf16)
//         then accumulate accF2 += h-slice @ Wf2[:, h*256..+256]^T
// LDS ~70 KB -> 2 blocks/CU.
#define HS2_LD 264  // 64 x 264 u16
#define AS_LD 136   // 64 x 136 u16
#define WS_LD 72    // 128 x 72 u16

__global__ __launch_bounds__(512, 4)
void ffn_k(const u16* __restrict__ xb, const u16* __restrict__ wf1b,
           const float* __restrict__ bf1, const u16* __restrict__ wf2b,
           const float* __restrict__ bf2, const float* __restrict__ accbuf,
           const float* __restrict__ g1, const float* __restrict__ be1,
           float* __restrict__ acc2, u16* __restrict__ x2b)
{
  __shared__ u16 Hs[64*HS2_LD];
  __shared__ u16 As[64*AS_LD];
  __shared__ u16 Ws[128*WS_LD];
  __shared__ __align__(16) float sA[128], sB[128];
  __shared__ float pS[128], pQ[128];

  const int t = threadIdx.x;
  const int row0 = blockIdx.x * 64;
  load_ab(accbuf, g1, be1, sA, sB, t);   // BN1 affine (includes __syncthreads)

  // ---- stage A = BN1(xb[row0 .. row0+64][0:128]) into As, once ----
  {
    const int r = t >> 3, seg = (t & 7) * 16;   // 16 values / thread
    const u16* src = xb + (size_t)(row0 + r) * 128 + seg;
    u16* dst = As + r * AS_LD + seg;
#pragma unroll
    for (int h = 0; h < 2; ++h) {
      const short8 x8 = *(const short8*)(src + h*8);
      const int c = seg + h*8;
      const float4 A0 = *(const float4*)&sA[c], A1 = *(const float4*)&sA[c+4];
      const float4 B0 = *(const float4*)&sB[c], B1 = *(const float4*)&sB[c+4];
      short8 s;
      s[0]=(short)f2b(b2f((u16)x8[0])*A0.x+B0.x); s[1]=(short)f2b(b2f((u16)x8[1])*A0.y+B0.y);
      s[2]=(short)f2b(b2f((u16)x8[2])*A0.z+B0.z); s[3]=(short)f2b(b2f((u16)x8[3])*A0.w+B0.w);
      s[4]=(short)f2b(b2f((u16)x8[4])*A1.x+B1.x); s[5]=(short)f2b(b2f((u16)x8[5])*A1.y+B1.y);
      s[6]=(short)f2b(b2f((u16)x8[6])*A1.z+B1.z); s[7]=(short)f2b(b2f((u16)x8[7])*A1.w+B1.w);
      *(short8*)(dst + h*8) = s;
    }
  }

  const int w = t >> 6, L = t & 63, lm = L & 15, lg = L >> 4;
  const int wcol = w * 16;            // 8 waves x 16 cols = 128 output cols
  const int wr = t >> 2, kc = (t & 3) * 16;   // W staging: 128 rows x 64 k / 512 thr

  // global chunk g in [0,16): half = g>>3, cc = g&7.
  // cc<4 -> ffn1 W chunk: hidden tile ct = 2*half + (cc>>1), k0 = (cc&1)*64
  // cc>=4 -> ffn2 W chunk: k window = half*256 + (cc-4)*64
  auto wsrc = [&](int g) -> const u16* {
    const int half = g >> 3, cc = g & 7;
    if (cc < 4) return wf1b + (size_t)((2*half + (cc>>1))*128 + wr)*128 + (cc&1)*64 + kc;
    return wf2b + (size_t)wr*512 + half*256 + (cc-4)*64 + kc;
  };

  f32x4 accF[4];   // ffn1 accumulator (reset per hidden col-tile)
  f32x4 acc2r[4];  // ffn2 accumulator (persists across both halves)
#pragma unroll
  for (int i = 0; i < 4; ++i) {
    accF[i]  = (f32x4){0.f,0.f,0.f,0.f};
    acc2r[i] = (f32x4){0.f,0.f,0.f,0.f};
  }

  short8 gw0 = *(const short8*)(wsrc(0));
  short8 gw1 = *(const short8*)(wsrc(0) + 8);

  for (int g = 0; g < 16; ++g) {
    const int cc = g & 7;
    const bool is1 = (cc < 4);
    __syncthreads();                       // Ws (and As/Hs writes) consumed/visible
    *(short8*)(Ws + wr*WS_LD + kc)     = gw0;
    *(short8*)(Ws + wr*WS_LD + kc + 8) = gw1;
    __syncthreads();
    if (g < 15) {                          // prefetch next W chunk
      gw0 = *(const short8*)(wsrc(g+1));
      gw1 = *(const short8*)(wsrc(g+1) + 8);
    }
    const u16* Abase = is1 ? (As + ((size_t)(cc & 1) * 64))
                           : (Hs + ((size_t)(cc - 4) * 64));
    const int ald = is1 ? AS_LD : HS2_LD;
#pragma unroll
    for (int ks = 0; ks < 64; ks += 32) {
      short8 af[4], wf;
#pragma unroll
      for (int i = 0; i < 4; ++i)
        af[i] = *(const short8*)(Abase + (i*16 + lm) * ald + ks + lg*8);
      wf = *(const short8*)(Ws + (wcol + lm) * WS_LD + ks + lg*8);
      if (is1) {
#pragma unroll
        for (int i = 0; i < 4; ++i)
          accF[i] = __builtin_amdgcn_mfma_f32_16x16x32_bf16(af[i], wf, accF[i], 0, 0, 0);
      } else {
#pragma unroll
        for (int i = 0; i < 4; ++i)
          acc2r[i] = __builtin_amdgcn_mfma_f32_16x16x32_bf16(af[i], wf, acc2r[i], 0, 0, 0);
      }
    }
    if (is1 && (cc & 1)) {                 // ffn1 col-tile done -> relu+bias -> Hs
      const int half = g >> 3;
      const int ct = 2*half + (cc >> 1);   // global hidden tile
      const int lct = cc >> 1;             // local tile within this half (0/1)
      const float b1 = bf1[ct*128 + wcol + lm];
#pragma unroll
      for (int i = 0; i < 4; ++i) {
#pragma unroll
        for (int r = 0; r < 4; ++r) {
          const int row = i*16 + lg*4 + r;
          Hs[row*HS2_LD + lct*128 + wcol + lm] = f2b(fmaxf(accF[i][r] + b1, 0.f));
        }
        accF[i] = (f32x4){0.f,0.f,0.f,0.f};
      }
    }
  }

  // ---- ffn2 epilogue: + BN1(xb) residual, BN2 stats, store x2b ----
  const int col = wcol + lm;
  const float b2 = bf2[col];
  const float ra = sA[col], rb = sB[col];
  float stS = 0.f, stQ = 0.f;
#pragma unroll
  for (int i = 0; i < 4; ++i) {
#pragma unroll
    for (int r = 0; r < 4; ++r) {
      const int row = row0 + i*16 + lg*4 + r;
      float v = acc2r[i][r] + b2 + b2f(xb[(size_t)row*128 + col]) * ra + rb;
      stS += v; stQ += v*v;
      x2b[(size_t)row*128 + col] = f2b(v);
    }
  }
  __syncthreads();
  if (t < 128) { pS[t] = 0.f; pQ[t] = 0.f; }
  __syncthreads();
  atomicAdd(&pS[col], stS);
  atomicAdd(&pQ[col], stQ);
  __syncthreads();
  if (t < 128) {
    atomicAdd(&acc2[t],       pS[t]);
    atomicAdd(&acc2[128 + t], pQ[t]);
  }
}

// ---------- attention: 1 block per (t,m), 4 waves, f16 16x16x16 MFMA ----------
__global__ __launch_bounds__(256)
void attn_k(const u16* __restrict__ q, const u16* __restrict__ k,
            const u16* __restrict__ v, u16* __restrict__ ab)
{
  __shared__ __align__(16) u16 Qs[256*QKS];
  __shared__ __align__(16) u16 Ks[256*QKS];
  __shared__ __align__(16) u16 Vt[16*264];
  const int tm = blockIdx.x, tt = tm >> 3, m = tm & 7;
  const int t = threadIdx.x;

  const uint4* qg = (const uint4*)(q + (size_t)tm*4096);
  const uint4* kg = (const uint4*)(k + (size_t)tm*4096);
  const uint4* vg = (const uint4*)(v + (size_t)tm*4096);
#pragma unroll
  for (int p = t; p < 512; p += 256) {
    const uint4 a = qg[p], b = kg[p], c = vg[p];
    const int row = p >> 1, h = (p & 1) * 8;
    *(uint4*)(Qs + row*QKS + h) = a;
    *(uint4*)(Ks + row*QKS + h) = b;
    *(uint4*)(Vt + (p >> 5)*264 + (p & 31)*8) = c;
  }
  __syncthreads();

  const int w = t >> 6, L = t & 63, lm = L & 15, quad = L >> 4;

  half4 vf[16];
#pragma unroll
  for (int jt = 0; jt < 16; ++jt)
    vf[jt] = *(const half4*)(Vt + lm*264 + jt*16 + quad*4);

  for (int nt = 0; nt < 4; ++nt) {
    const half4 bq = *(const half4*)(Qs + ((w*4 + nt)*16 + lm)*QKS + quad*4);
    f32x4 s[16];
#pragma unroll
    for (int jt = 0; jt < 16; ++jt) {
      const half4 af = *(const half4*)(Ks + (jt*16 + lm)*QKS + quad*4);
      s[jt] = __builtin_amdgcn_mfma_f32_16x16x16f16(af, bq, (f32x4){0.f,0.f,0.f,0.f}, 0, 0, 0);
    }
    float mx = s[0][0];
#pragma unroll
    for (int jt = 0; jt < 16; ++jt)
#pragma unroll
      for (int r = 0; r < 4; ++r) mx = fmaxf(mx, s[jt][r]);
    mx = fmaxf(mx, __shfl_xor(mx, 16));
    mx = fmaxf(mx, __shfl_xor(mx, 32));
    float ls = 0.f;
#pragma unroll
    for (int jt = 0; jt < 16; ++jt)
#pragma unroll
      for (int r = 0; r < 4; ++r) { const float p = exp2f(s[jt][r] - mx); s[jt][r] = p; ls += p; }
    ls += __shfl_xor(ls, 16);
    ls += __shfl_xor(ls, 32);

    f32x4 oacc = {0.f,0.f,0.f,0.f};
#pragma unroll
    for (int jt = 0; jt < 16; ++jt) {
      half4 pf;
      pf[0] = (_Float16)s[jt][0]; pf[1] = (_Float16)s[jt][1];
      pf[2] = (_Float16)s[jt][2]; pf[3] = (_Float16)s[jt][3];
      oacc = __builtin_amdgcn_mfma_f32_16x16x16f16(pf, vf[jt], oacc, 0, 0, 0);
    }
    const int q0 = w*64 + nt*16 + quad*4;
#pragma unroll
    for (int r = 0; r < 4; ++r) {
      const float lr = __shfl(ls, quad*4 + r);
      ab[((size_t)tt*256 + q0 + r)*128 + m*16 + lm] = f2b(oacc[r] / lr);
    }
  }
}

// ---------- final: BN2 affine + apply bf16 -> fp32 out (512 blocks, uint2 loads) ----------
__global__ __launch_bounds__(256)
void bn_final(const uint2* __restrict__ x2, const float* __restrict__ gacc,
              const float* __restrict__ gam, const float* __restrict__ bet,
              float* __restrict__ out)
{
  __shared__ __align__(16) float sA[128], sB[128];
  const int t = threadIdx.x;
  load_ab(gacc, gam, bet, sA, sB, t);
#pragma unroll 2
  for (int kk = 0; kk < 8; ++kk) {
    const size_t idx = (size_t)blockIdx.x * 2048 + kk * 256 + t;
    const uint2 u = x2[idx];
    const int c = (int)((idx & 31) * 4);   // 4 consecutive channels, 16B aligned
    const f32x4 A = *(const f32x4*)&sA[c];
    const f32x4 B = *(const f32x4*)&sB[c];
    f32x4 o;
    o[0] = BLO(u.x)*A[0] + B[0];
    o[1] = BHI(u.x)*A[1] + B[1];
    o[2] = BLO(u.y)*A[2] + B[2];
    o[3] = BHI(u.y)*A[3] + B[3];
    *(f32x4*)(out + idx*4) = o;
  }
}

// ---------- launch: 5 nodes ----------
extern "C" void kernel_launch(void* const* d_in, const int* in_sizes, int n_in,
                              void* d_out, int out_size, void* d_ws, size_t ws_size,
                              hipStream_t stream)
{
  (void)in_sizes; (void)n_in; (void)out_size; (void)ws_size;
  const float* node = (const float*)d_in[0];
  const float* Wq  = (const float*)d_in[1];  const float* bq  = (const float*)d_in[2];
  const float* Wk  = (const float*)d_in[3];  const float* bk  = (const float*)d_in[4];
  const float* Wv  = (const float*)d_in[5];  const float* bv  = (const float*)d_in[6];
  const float* Ww  = (const float*)d_in[7];  const float* bw  = (const float*)d_in[8];
  const float* Wf1 = (const float*)d_in[9];  const float* bf1 = (const float*)d_in[10];
  const float* Wf2 = (const float*)d_in[11]; const float* bf2 = (const float*)d_in[12];
  const float* g1  = (const float*)d_in[13]; const float* be1 = (const float*)d_in[14];
  const float* g2  = (const float*)d_in[15]; const float* be2 = (const float*)d_in[16];
  float* out = (float*)d_out;
  char* ws = (char*)d_ws;

  // workspace (bytes)
  u16* wb  = (u16*)(ws + 0);          // weights bf16 concat (Ww@49152, Wf1@65536, Wf2@131072 u16)
  u16* qb  = (u16*)(ws + 524288);     // q f16 [T][M][N][D] (pre-scaled)
  u16* kb  = (u16*)(ws + 8912896);    // k f16 [T][M][N][D]
  u16* vb  = (u16*)(ws + 17301504);   // v f16 [T][M][D][N]
  u16* ab  = (u16*)(ws + 25690112);   // attn out bf16 [T][N][E]
  u16* xb  = (u16*)(ws + 34078720);   // x (pre-BN1) bf16
  u16* x2b = (u16*)(ws + 42467328);   // x2 (pre-BN2) bf16
  float* accbuf = (float*)(ws + 50855936);  // 512 floats: sum1,sq1,sum2,sq2

  u16* wwb = wb + 49152;  u16* wf1b = wb + 65536; u16* wf2b = wb + 131072;

  dim3 blk(256);

  // 1. fused QKV (256 tiles) + cvt(Ww,Wf1,Wf2) (144) + zero accbuf (1) = 401 blocks
  qkv_k<<<dim3(401), blk, 0, stream>>>(node, Wq,bq, Wk,bk, Wv,bv, Ww, Wf1, Wf2,
                                       qb, kb, vb, wb, accbuf);
  // 2. attention
  attn_k<<<dim3(1024), blk, 0, stream>>>(qb, kb, vb, ab);
  // 3. out-proj + node residual -> xb, BN1 sums -> accbuf[0..256)
  oproj_k<<<dim3(256,2), blk, 0, stream>>>(ab, wwb, bw, node, accbuf, xb);
  // 4. fused FFN1+FFN2 v3 (2-half hidden in LDS, 2 blocks/CU) -> x2b, BN2 sums
  ffn_k<<<dim3(512), dim3(512), 0, stream>>>(xb, wf1b, bf1, wf2b, bf2,
                                             accbuf, g1, be1, accbuf + 256, x2b);
  // 5. BN2 apply -> fp32 out
  bn_final<<<dim3(512), blk, 0, stream>>>((const uint2*)x2b, accbuf + 256, g2, be2, out);
}